// Round 26
// baseline (283.169 us; speedup 1.0000x reference)
//
#include <hip/hip_runtime.h>
#include <hip/hip_bf16.h>
#include <stdint.h>

// GraphConv x2 — round 26: r25 base (239.9us best) + ONE change:
//   gather1_fused epilogue processes BOTH rows inside the k-loop sharing each
//   weight-LDS read (128 reads/row-pair instead of 256). FMA count unchanged.
// N=100000, E=1600000, D=64

#define D 64
#define EPB   2048     // edges per binA tile (16KB LDS)
#define EPT   4        // edges per thread in binA
#define NBMAX 256
#define CAPB  10240
#define GW 8
#define GR 4
#define AW 8

typedef unsigned int   u32;
typedef unsigned short u16;

__device__ __forceinline__ float bf2f(u16 v) {
    return __uint_as_float(((u32)v) << 16);
}
__device__ __forceinline__ u16 f2bf(float f) {
    u32 u = __float_as_uint(f);
    u32 r = (u + 0x7fffu + ((u >> 16) & 1u)) >> 16;   // round-to-nearest-even
    return (u16)r;
}

// ---------------- binA: LDS-binned edge scatter (r24/r25 verbatim) ----------------
__global__ __launch_bounds__(512) void binA_kernel(
    const int* __restrict__ ei, const float* __restrict__ ew,
    int* __restrict__ bucketCnt, uint64_t* __restrict__ bucketBuf, int E_, int nb)
{
    __shared__ uint64_t lds_e[EPB];      // 16 KB
    __shared__ int lcnt[NBMAX];
    __shared__ int loff[NBMAX];
    __shared__ int gbase[NBMAX];

    int tid  = threadIdx.x;
    int tile = blockIdx.x * EPB;
    int cnt  = min(EPB, E_ - tile);
    if (cnt <= 0) return;

    for (int k = tid; k < nb; k += 512) lcnt[k] = 0;
    __syncthreads();

    bool     val[EPT];
    int      lp[EPT], bk[EPT];
    uint64_t ent[EPT];
#pragma unroll
    for (int j = 0; j < EPT; ++j) {
        int l = j * 512 + tid;
        val[j] = (l < cnt);
        if (val[j]) {
            int e   = tile + l;
            int src = ei[e];
            int dst = ei[E_ + e];
            u32 wb  = (u32)f2bf(ew[e]) & 0x7FFFu;
            u32 p32 = ((u32)src << 15) | wb;               // r17 pack
            int b   = dst >> 9;
            ent[j] = ((uint64_t)(u32)dst << 32) | p32;
            bk[j]  = b;
            lp[j]  = atomicAdd(&lcnt[b], 1);               // LDS atomic
        }
    }
    __syncthreads();

    if (tid == 0) {                                        // exclusive scan
        int run = 0;
        for (int b = 0; b < nb; ++b) { int c = lcnt[b]; loff[b] = run; run += c; }
    }
    __syncthreads();
    if (tid < nb) gbase[tid] = atomicAdd(&bucketCnt[tid], lcnt[tid]);
    __syncthreads();

#pragma unroll
    for (int j = 0; j < EPT; ++j)
        if (val[j]) lds_e[loff[bk[j]] + lp[j]] = ent[j];   // group by bucket in LDS
    __syncthreads();

    for (int k = tid; k < cnt; k += 512) {
        uint64_t en = lds_e[k];
        int b   = (int)(en >> 41);                         // dst>>9
        int gp  = gbase[b] + (k - loff[b]);
        if (gp < CAPB)
            bucketBuf[(size_t)b * CAPB + gp] = en;
    }
}

// ---------------- degscan: per-bucket histogram + exclusive scan (r25 verbatim) ----------------
__global__ __launch_bounds__(256) void degscan_kernel(
    const uint64_t* __restrict__ bucketBuf, const int* __restrict__ bucketCnt,
    int* __restrict__ loc, int* __restrict__ bucketTot, int nb, int Nn)
{
    __shared__ int ldeg[512];
    __shared__ int wsum[4];
    int b = blockIdx.x;
    if (b >= nb) return;
    int node0 = b << 9;
    int tid = threadIdx.x;
    for (int k = tid; k < 512; k += 256) ldeg[k] = 0;
    __syncthreads();

    int cnt = min(bucketCnt[b], CAPB);
    for (int k = tid; k < cnt; k += 256)
        atomicAdd(&ldeg[((int)(bucketBuf[(size_t)b * CAPB + k] >> 32)) - node0], 1);
    __syncthreads();

    int v0 = ldeg[2 * tid], v1 = ldeg[2 * tid + 1];
    int s = v0 + v1;
    int lane = tid & 63, wave = tid >> 6;
    int inc = s;
    for (int off = 1; off < 64; off <<= 1) {
        int u = __shfl_up(inc, off);
        if (lane >= off) inc += u;
    }
    if (lane == 63) wsum[wave] = inc;
    __syncthreads();
    int woff = 0;
    for (int w2 = 0; w2 < wave; ++w2) woff += wsum[w2];
    int ex = woff + inc - s;
    int n0 = node0 + 2 * tid;
    if (n0 < Nn)     loc[n0]     = ex;
    if (n0 + 1 < Nn) loc[n0 + 1] = ex + v0;
    if (tid == 255) bucketTot[b] = woff + inc;
}

// ---------------- scan2 (r25 verbatim) ----------------
__global__ __launch_bounds__(1024) void scan2_kernel(int* __restrict__ partial, int nchunk)
{
    __shared__ int sd[1024];
    int t = threadIdx.x;
    if (t < nchunk) sd[t] = partial[t];
    __syncthreads();
    if (t == 0) {
        int run = 0;
        for (int i = 0; i < nchunk; ++i) { int v = sd[i]; sd[i] = run; run += v; }
    }
    __syncthreads();
    if (t < nchunk) partial[t] = sd[t];
}

// ---------------- binB2 (r25 verbatim) ----------------
__global__ __launch_bounds__(256) void binB2_kernel(
    const uint64_t* __restrict__ bucketBuf, const int* __restrict__ bucketCnt,
    const int* __restrict__ loc, const int* __restrict__ partial,
    int* __restrict__ rowptr, u32* __restrict__ pairs, int nb, int Nn, int E_)
{
    __shared__ int lcur[512];
    int b = blockIdx.x;
    if (b >= nb) return;
    int node0 = b << 9;
    int tid = threadIdx.x;
    int base = partial[b];
    for (int k = tid; k < 512; k += 256) {
        int node = node0 + k;
        if (node < Nn) {
            int v = loc[node] + base;
            lcur[k] = v;
            rowptr[node] = v;
        }
    }
    if (b == nb - 1 && tid == 0) rowptr[Nn] = E_;
    __syncthreads();

    int cnt = min(bucketCnt[b], CAPB);
    for (int k = tid; k < cnt; k += 256) {
        uint64_t en = bucketBuf[(size_t)b * CAPB + k];
        int dst = (int)(en >> 32);
        int p = atomicAdd(&lcur[dst - node0], 1);          // LDS atomic
        pairs[p] = (u32)en;                                // bucket-local region
    }
}

// ---------------- gemm1 (r18/r25 verbatim, proven) ----------------
__global__ __launch_bounds__(512) void gemm_kernel(
    const float* xin,
    const float* __restrict__ Wrel, const float* __restrict__ brel,
    const float* __restrict__ Wroot,
    u16* __restrict__ xr, float* io, int Nn)
{
    __shared__ float WrelT[D][D + 1];
    __shared__ float WrootT[D][D + 1];
    __shared__ float bias[D];
    __shared__ float rowX[GW][GR][D];

    int tid = threadIdx.x;
    for (int i = tid; i < D * D; i += 512) {
        int d = i >> 6, k = i & 63;
        WrelT [k][d] = Wrel [i];
        WrootT[k][d] = Wroot[i];
    }
    if (tid < D) bias[tid] = brel[tid];
    __syncthreads();

    int wave = tid >> 6, lane = tid & 63;

    int base = (blockIdx.x * GW + wave) * GR;
    if (base >= Nn) return;             // wave-uniform, after barrier
    int nr = min(GR, Nn - base);

    for (int r = 0; r < nr; ++r)
        rowX[wave][r][lane] = xin[(size_t)(base + r) * D + lane];
    // same-wave LDS write->read (proven)

    float aR[GR] = {0.f, 0.f, 0.f, 0.f};
    float aC[GR] = {0.f, 0.f, 0.f, 0.f};
#pragma unroll
    for (int k4 = 0; k4 < 16; ++k4) {
        float4 xv[GR];
#pragma unroll
        for (int r = 0; r < GR; ++r)
            xv[r] = *reinterpret_cast<const float4*>(&rowX[wave][r][k4 * 4]);
#pragma unroll
        for (int kk = 0; kk < 4; ++kk) {
            float wr = WrelT [k4 * 4 + kk][lane];
            float wc = WrootT[k4 * 4 + kk][lane];
#pragma unroll
            for (int r = 0; r < GR; ++r) {
                float xk = (kk == 0) ? xv[r].x : (kk == 1) ? xv[r].y
                         : (kk == 2) ? xv[r].z : xv[r].w;
                aR[r] = fmaf(xk, wr, aR[r]);
                aC[r] = fmaf(xk, wc, aC[r]);
            }
        }
    }
    for (int r = 0; r < nr; ++r) {
        size_t o = (size_t)(base + r) * D + lane;
        xr[o] = f2bf(aR[r]);
        io[o] = aC[r] + bias[lane];
    }
}

// ---------------- gather1_fused: 2-row gather + WEIGHT-SHARED 2-row epilogue ----------------
__global__ __launch_bounds__(512) void gather1_fused(
    const u16* __restrict__ xr1, const u32* __restrict__ pairs,
    const int* __restrict__ rowptr,
    const float* __restrict__ Wrel, const float* __restrict__ brel,
    const float* __restrict__ Wroot,
    u16* __restrict__ xr2, float* __restrict__ io, int Nn)
{
    __shared__ float WrelT[D][D + 1];
    __shared__ float WrootT[D][D + 1];
    __shared__ float bias[D];
    __shared__ float rowH[GW][2][D];

    int tid = threadIdx.x;
    for (int i2 = tid; i2 < D * D; i2 += 512) {
        int d = i2 >> 6, k = i2 & 63;
        WrelT [k][d] = Wrel [i2];
        WrootT[k][d] = Wroot[i2];
    }
    if (tid < D) bias[tid] = brel[tid];
    __syncthreads();

    int wave = tid >> 6, lane = tid & 63;
    int i0 = ((int)blockIdx.x * GW + wave) * 2;
    if (i0 >= Nn) return;                      // wave-uniform, after barrier
    int i1 = i0 + 1;
    bool row1v = (i1 < Nn);
    int i1c = row1v ? i1 : i0;

    int beg0 = __builtin_amdgcn_readfirstlane(rowptr[i0]);
    int end0 = __builtin_amdgcn_readfirstlane(rowptr[i0 + 1]);
    int beg1 = __builtin_amdgcn_readfirstlane(rowptr[i1c]);
    int end1 = __builtin_amdgcn_readfirstlane(rowptr[i1c + 1]);
    int deg0 = end0 - beg0;
    int deg1 = row1v ? (end1 - beg1) : 0;
    int dmax = max(deg0, deg1);

    int half = lane >> 5;                      // 0: edge j, 1: edge j+1
    int c    = lane & 31;                      // feature pair index

    float a00 = 0.f, a01 = 0.f, a10 = 0.f, a11 = 0.f;
    for (int b = 0; b < dmax; b += 16) {       // 16 edge-slots/row/volley
#pragma unroll
        for (int jj = 0; jj < 8; ++jj) {
            int j0 = b + 2 * jj;
            u32 q0 = pairs[beg0 + j0];
            u32 q1 = pairs[beg0 + j0 + 1];
            int   s00 = (j0     < deg0) ? (int)(q0 >> 15) : 0;
            float w00 = (j0     < deg0) ? __uint_as_float((q0 & 0x7FFFu) << 16) : 0.f;
            int   s01 = (j0 + 1 < deg0) ? (int)(q1 >> 15) : 0;
            float w01 = (j0 + 1 < deg0) ? __uint_as_float((q1 & 0x7FFFu) << 16) : 0.f;
            int   sa  = half ? s01 : s00;
            float wa  = half ? w01 : w00;
            u32 va = *reinterpret_cast<const u32*>(xr1 + (size_t)sa * D + c * 2);
            u32 r0 = pairs[beg1 + j0];
            u32 r1 = pairs[beg1 + j0 + 1];
            int   s10 = (j0     < deg1) ? (int)(r0 >> 15) : 0;
            float w10 = (j0     < deg1) ? __uint_as_float((r0 & 0x7FFFu) << 16) : 0.f;
            int   s11 = (j0 + 1 < deg1) ? (int)(r1 >> 15) : 0;
            float w11 = (j0 + 1 < deg1) ? __uint_as_float((r1 & 0x7FFFu) << 16) : 0.f;
            int   sb  = half ? s11 : s10;
            float wb  = half ? w11 : w10;
            u32 vb = *reinterpret_cast<const u32*>(xr1 + (size_t)sb * D + c * 2);

            a00 = fmaf(__uint_as_float(va << 16),          wa, a00);
            a01 = fmaf(__uint_as_float(va & 0xFFFF0000u),  wa, a01);
            a10 = fmaf(__uint_as_float(vb << 16),          wb, a10);
            a11 = fmaf(__uint_as_float(vb & 0xFFFF0000u),  wb, a11);
        }
    }
    a00 += __shfl_xor(a00, 32);                // combine edge-halves
    a01 += __shfl_xor(a01, 32);
    a10 += __shfl_xor(a10, 32);
    a11 += __shfl_xor(a11, 32);

    if (lane < 32) {                           // feature-major staging
        *reinterpret_cast<float2*>(&rowH[wave][0][c * 2]) = make_float2(a00, a01);
        *reinterpret_cast<float2*>(&rowH[wave][1][c * 2]) = make_float2(a10, a11);
    }
    // same-wave LDS write->read (proven)

    size_t o0 = (size_t)i0 * D + lane;
    float h0 = fmaxf(rowH[wave][0][lane] + io[o0], 0.f);
    rowH[wave][0][lane] = h0;
    size_t o1 = (size_t)i1c * D + lane;
    float h1 = fmaxf(rowH[wave][1][lane] + io[o1], 0.f);
    rowH[wave][1][lane] = h1;                  // (dup of row0 when !row1v; never stored)

    // ---- weight-shared 2-row epilogue: each WrelT/WrootT read feeds BOTH rows ----
    const float4* rH0 = reinterpret_cast<const float4*>(rowH[wave][0]);
    const float4* rH1 = reinterpret_cast<const float4*>(rowH[wave][1]);
    float aR0 = 0.f, aC0 = bias[lane];
    float aR1 = 0.f, aC1 = bias[lane];
#pragma unroll
    for (int k4 = 0; k4 < 16; ++k4) {
        float4 h0v = rH0[k4];                  // broadcast b128
        float4 h1v = rH1[k4];
        int k = k4 * 4;
        float wr0 = WrelT [k + 0][lane], wc0 = WrootT[k + 0][lane];
        aR0 = fmaf(h0v.x, wr0, aR0); aC0 = fmaf(h0v.x, wc0, aC0);
        aR1 = fmaf(h1v.x, wr0, aR1); aC1 = fmaf(h1v.x, wc0, aC1);
        float wr1 = WrelT [k + 1][lane], wc1 = WrootT[k + 1][lane];
        aR0 = fmaf(h0v.y, wr1, aR0); aC0 = fmaf(h0v.y, wc1, aC0);
        aR1 = fmaf(h1v.y, wr1, aR1); aC1 = fmaf(h1v.y, wc1, aC1);
        float wr2 = WrelT [k + 2][lane], wc2 = WrootT[k + 2][lane];
        aR0 = fmaf(h0v.z, wr2, aR0); aC0 = fmaf(h0v.z, wc2, aC0);
        aR1 = fmaf(h1v.z, wr2, aR1); aC1 = fmaf(h1v.z, wc2, aC1);
        float wr3 = WrelT [k + 3][lane], wc3 = WrootT[k + 3][lane];
        aR0 = fmaf(h0v.w, wr3, aR0); aC0 = fmaf(h0v.w, wc3, aC0);
        aR1 = fmaf(h1v.w, wr3, aR1); aC1 = fmaf(h1v.w, wc3, aC1);
    }
    xr2[o0] = f2bf(aR0);
    io[o0]  = aC0;                             // rows owned by this wave
    if (row1v) {
        size_t o1w = (size_t)i1 * D + lane;
        xr2[o1w] = f2bf(aR1);
        io[o1w]  = aC1;
    }
}

// ---------------- gather2 (r20/r25 verbatim) ----------------
__global__ __launch_bounds__(512) void gather2_kernel(
    const u16* __restrict__ xr, const u32* __restrict__ pairs,
    const int* __restrict__ rowptr, float* __restrict__ io, int Nn)
{
    int tid  = threadIdx.x;
    int wave = tid >> 6, lane = tid & 63;
    int i0 = ((int)blockIdx.x * AW + wave) * 2;
    if (i0 >= Nn) return;                      // wave-uniform
    int i1 = i0 + 1;
    bool row1v = (i1 < Nn);
    int i1c = row1v ? i1 : i0;

    int beg0 = __builtin_amdgcn_readfirstlane(rowptr[i0]);
    int end0 = __builtin_amdgcn_readfirstlane(rowptr[i0 + 1]);
    int beg1 = __builtin_amdgcn_readfirstlane(rowptr[i1c]);
    int end1 = __builtin_amdgcn_readfirstlane(rowptr[i1c + 1]);
    int deg0 = end0 - beg0;
    int deg1 = row1v ? (end1 - beg1) : 0;
    int dmax = max(deg0, deg1);

    int half = lane >> 5;
    int c    = lane & 31;

    float a00 = 0.f, a01 = 0.f, a10 = 0.f, a11 = 0.f;
    for (int b = 0; b < dmax; b += 16) {
#pragma unroll
        for (int jj = 0; jj < 8; ++jj) {
            int j0 = b + 2 * jj;
            u32 q0 = pairs[beg0 + j0];
            u32 q1 = pairs[beg0 + j0 + 1];
            int   s00 = (j0     < deg0) ? (int)(q0 >> 15) : 0;
            float w00 = (j0     < deg0) ? __uint_as_float((q0 & 0x7FFFu) << 16) : 0.f;
            int   s01 = (j0 + 1 < deg0) ? (int)(q1 >> 15) : 0;
            float w01 = (j0 + 1 < deg0) ? __uint_as_float((q1 & 0x7FFFu) << 16) : 0.f;
            int   sa  = half ? s01 : s00;
            float wa  = half ? w01 : w00;
            u32 va = *reinterpret_cast<const u32*>(xr + (size_t)sa * D + c * 2);
            u32 r0 = pairs[beg1 + j0];
            u32 r1 = pairs[beg1 + j0 + 1];
            int   s10 = (j0     < deg1) ? (int)(r0 >> 15) : 0;
            float w10 = (j0     < deg1) ? __uint_as_float((r0 & 0x7FFFu) << 16) : 0.f;
            int   s11 = (j0 + 1 < deg1) ? (int)(r1 >> 15) : 0;
            float w11 = (j0 + 1 < deg1) ? __uint_as_float((r1 & 0x7FFFu) << 16) : 0.f;
            int   sb  = half ? s11 : s10;
            float wb  = half ? w11 : w10;
            u32 vb = *reinterpret_cast<const u32*>(xr + (size_t)sb * D + c * 2);

            a00 = fmaf(__uint_as_float(va << 16),         wa, a00);
            a01 = fmaf(__uint_as_float(va & 0xFFFF0000u), wa, a01);
            a10 = fmaf(__uint_as_float(vb << 16),         wb, a10);
            a11 = fmaf(__uint_as_float(vb & 0xFFFF0000u), wb, a11);
        }
    }
    a00 += __shfl_xor(a00, 32);
    a01 += __shfl_xor(a01, 32);
    a10 += __shfl_xor(a10, 32);
    a11 += __shfl_xor(a11, 32);

    if (lane < 32) {
        float2* p0 = reinterpret_cast<float2*>(&io[(size_t)i0 * D + c * 2]);
        float2 c0 = *p0; c0.x += a00; c0.y += a01; *p0 = c0;
        if (row1v) {
            float2* p1 = reinterpret_cast<float2*>(&io[(size_t)i1 * D + c * 2]);
            float2 c1 = *p1; c1.x += a10; c1.y += a11; *p1 = c1;
        }
    }
}

extern "C" void kernel_launch(void* const* d_in, const int* in_sizes, int n_in,
                              void* d_out, int out_size, void* d_ws, size_t ws_size,
                              hipStream_t stream)
{
    const float* x      = (const float*)d_in[0];
    const int*   ei     = (const int*)  d_in[1];
    const float* ew     = (const float*)d_in[2];
    const float* Wrel1  = (const float*)d_in[3];
    const float* brel1  = (const float*)d_in[4];
    const float* Wroot1 = (const float*)d_in[5];
    const float* Wrel2  = (const float*)d_in[6];
    const float* brel2  = (const float*)d_in[7];
    const float* Wroot2 = (const float*)d_in[8];
    float* out = (float*)d_out;

    const int E_ = in_sizes[2];          // 1600000
    const int Nn = in_sizes[0] / D;      // 100000
    const int nb = (Nn + 511) >> 9;      // 196 buckets

    // workspace layout (~33 MB; bucketBuf 16.1MB ALIASES xr1/xr2 — dead until gemm1)
    char* w = (char*)d_ws;
    size_t off = 0;
    u16*  xr1    = (u16*)(w + off); off += (size_t)Nn * D * sizeof(u16);   // 12.8 MB
    u16*  xr2    = (u16*)(w + off); off += (size_t)Nn * D * sizeof(u16);   // 12.8 MB
    uint64_t* bucketBuf = (uint64_t*)d_ws;                                 // alias, 16.1 MB
    int*  rowptr = (int*)(w + off); off += (size_t)(Nn + 1) * sizeof(int);
    int*  loc    = (int*)(w + off); off += (size_t)Nn * sizeof(int);
    int*  bucketCnt = (int*)(w + off); off += NBMAX * sizeof(int);
    int*  partial= (int*)(w + off); off += 1024 * sizeof(int);
    off = (off + 15) & ~(size_t)15;
    u32* pairs = (u32*)(w + off);                                          // 6.4 MB + 256B pad

    const int aBlocks = (E_ + EPB - 1) / EPB;            // 782
    const int gemmBlocks = (Nn + GW * GR - 1) / (GW * GR);
    const int g1Blocks   = (Nn + GW * 2 - 1) / (GW * 2); // 2 rows/wave
    const int g2Blocks   = (Nn + AW * 2 - 1) / (AW * 2);

    // ---- binned CSR build (5 dispatches) ----
    (void)hipMemsetAsync(bucketCnt, 0, NBMAX * sizeof(int), stream);
    binA_kernel<<<aBlocks, 512, 0, stream>>>(ei, ew, bucketCnt, bucketBuf, E_, nb);
    degscan_kernel<<<nb, 256, 0, stream>>>(bucketBuf, bucketCnt, loc, partial, nb, Nn);
    scan2_kernel<<<1, 1024, 0, stream>>>(partial, nb);
    binB2_kernel<<<nb, 256, 0, stream>>>(bucketBuf, bucketCnt, loc, partial,
                                         rowptr, pairs, nb, Nn, E_);

    // ---- layer 1 pre-transform ----
    gemm_kernel<<<gemmBlocks, 512, 0, stream>>>(x, Wrel1, brel1, Wroot1, xr1, out, Nn);
    // ---- gather1 + relu + layer-2 pre-transform (weight-shared fused epilogue) ----
    gather1_fused<<<g1Blocks, 512, 0, stream>>>(xr1, pairs, rowptr,
                                                Wrel2, brel2, Wroot2, xr2, out, Nn);
    // ---- gather2 (final) ----
    gather2_kernel<<<g2Blocks, 512, 0, stream>>>(xr2, pairs, rowptr, out, Nn);
}

// Round 27
// 235.731 us; speedup vs baseline: 1.2012x; 1.2012x over previous
//
#include <hip/hip_runtime.h>
#include <hip/hip_bf16.h>
#include <stdint.h>

// GraphConv x2 — round 27: r25 base (239.9us best; r26's weight-shared epilogue
// reverted — VGPR 84/occ 21% regression) + ONE zero-VGPR-cost change:
//   two-row write-backs split across wave halves (both halves hold full sums
//   after shfl_xor(32); previously lanes 0-31 did both rows serially).
// N=100000, E=1600000, D=64

#define D 64
#define EPB   2048     // edges per binA tile (16KB LDS)
#define EPT   4        // edges per thread in binA
#define NBMAX 256
#define CAPB  10240
#define GW 8
#define GR 4
#define AW 8

typedef unsigned int   u32;
typedef unsigned short u16;

__device__ __forceinline__ float bf2f(u16 v) {
    return __uint_as_float(((u32)v) << 16);
}
__device__ __forceinline__ u16 f2bf(float f) {
    u32 u = __float_as_uint(f);
    u32 r = (u + 0x7fffu + ((u >> 16) & 1u)) >> 16;   // round-to-nearest-even
    return (u16)r;
}

// ---------------- binA: LDS-binned edge scatter (r24/r25 verbatim) ----------------
__global__ __launch_bounds__(512) void binA_kernel(
    const int* __restrict__ ei, const float* __restrict__ ew,
    int* __restrict__ bucketCnt, uint64_t* __restrict__ bucketBuf, int E_, int nb)
{
    __shared__ uint64_t lds_e[EPB];      // 16 KB
    __shared__ int lcnt[NBMAX];
    __shared__ int loff[NBMAX];
    __shared__ int gbase[NBMAX];

    int tid  = threadIdx.x;
    int tile = blockIdx.x * EPB;
    int cnt  = min(EPB, E_ - tile);
    if (cnt <= 0) return;

    for (int k = tid; k < nb; k += 512) lcnt[k] = 0;
    __syncthreads();

    bool     val[EPT];
    int      lp[EPT], bk[EPT];
    uint64_t ent[EPT];
#pragma unroll
    for (int j = 0; j < EPT; ++j) {
        int l = j * 512 + tid;
        val[j] = (l < cnt);
        if (val[j]) {
            int e   = tile + l;
            int src = ei[e];
            int dst = ei[E_ + e];
            u32 wb  = (u32)f2bf(ew[e]) & 0x7FFFu;
            u32 p32 = ((u32)src << 15) | wb;               // r17 pack
            int b   = dst >> 9;
            ent[j] = ((uint64_t)(u32)dst << 32) | p32;
            bk[j]  = b;
            lp[j]  = atomicAdd(&lcnt[b], 1);               // LDS atomic
        }
    }
    __syncthreads();

    if (tid == 0) {                                        // exclusive scan
        int run = 0;
        for (int b = 0; b < nb; ++b) { int c = lcnt[b]; loff[b] = run; run += c; }
    }
    __syncthreads();
    if (tid < nb) gbase[tid] = atomicAdd(&bucketCnt[tid], lcnt[tid]);
    __syncthreads();

#pragma unroll
    for (int j = 0; j < EPT; ++j)
        if (val[j]) lds_e[loff[bk[j]] + lp[j]] = ent[j];   // group by bucket in LDS
    __syncthreads();

    for (int k = tid; k < cnt; k += 512) {
        uint64_t en = lds_e[k];
        int b   = (int)(en >> 41);                         // dst>>9
        int gp  = gbase[b] + (k - loff[b]);
        if (gp < CAPB)
            bucketBuf[(size_t)b * CAPB + gp] = en;
    }
}

// ---------------- degscan (r25 verbatim) ----------------
__global__ __launch_bounds__(256) void degscan_kernel(
    const uint64_t* __restrict__ bucketBuf, const int* __restrict__ bucketCnt,
    int* __restrict__ loc, int* __restrict__ bucketTot, int nb, int Nn)
{
    __shared__ int ldeg[512];
    __shared__ int wsum[4];
    int b = blockIdx.x;
    if (b >= nb) return;
    int node0 = b << 9;
    int tid = threadIdx.x;
    for (int k = tid; k < 512; k += 256) ldeg[k] = 0;
    __syncthreads();

    int cnt = min(bucketCnt[b], CAPB);
    for (int k = tid; k < cnt; k += 256)
        atomicAdd(&ldeg[((int)(bucketBuf[(size_t)b * CAPB + k] >> 32)) - node0], 1);
    __syncthreads();

    int v0 = ldeg[2 * tid], v1 = ldeg[2 * tid + 1];
    int s = v0 + v1;
    int lane = tid & 63, wave = tid >> 6;
    int inc = s;
    for (int off = 1; off < 64; off <<= 1) {
        int u = __shfl_up(inc, off);
        if (lane >= off) inc += u;
    }
    if (lane == 63) wsum[wave] = inc;
    __syncthreads();
    int woff = 0;
    for (int w2 = 0; w2 < wave; ++w2) woff += wsum[w2];
    int ex = woff + inc - s;
    int n0 = node0 + 2 * tid;
    if (n0 < Nn)     loc[n0]     = ex;
    if (n0 + 1 < Nn) loc[n0 + 1] = ex + v0;
    if (tid == 255) bucketTot[b] = woff + inc;
}

// ---------------- scan2 (r25 verbatim) ----------------
__global__ __launch_bounds__(1024) void scan2_kernel(int* __restrict__ partial, int nchunk)
{
    __shared__ int sd[1024];
    int t = threadIdx.x;
    if (t < nchunk) sd[t] = partial[t];
    __syncthreads();
    if (t == 0) {
        int run = 0;
        for (int i = 0; i < nchunk; ++i) { int v = sd[i]; sd[i] = run; run += v; }
    }
    __syncthreads();
    if (t < nchunk) partial[t] = sd[t];
}

// ---------------- binB2 (r25 verbatim) ----------------
__global__ __launch_bounds__(256) void binB2_kernel(
    const uint64_t* __restrict__ bucketBuf, const int* __restrict__ bucketCnt,
    const int* __restrict__ loc, const int* __restrict__ partial,
    int* __restrict__ rowptr, u32* __restrict__ pairs, int nb, int Nn, int E_)
{
    __shared__ int lcur[512];
    int b = blockIdx.x;
    if (b >= nb) return;
    int node0 = b << 9;
    int tid = threadIdx.x;
    int base = partial[b];
    for (int k = tid; k < 512; k += 256) {
        int node = node0 + k;
        if (node < Nn) {
            int v = loc[node] + base;
            lcur[k] = v;
            rowptr[node] = v;
        }
    }
    if (b == nb - 1 && tid == 0) rowptr[Nn] = E_;
    __syncthreads();

    int cnt = min(bucketCnt[b], CAPB);
    for (int k = tid; k < cnt; k += 256) {
        uint64_t en = bucketBuf[(size_t)b * CAPB + k];
        int dst = (int)(en >> 32);
        int p = atomicAdd(&lcur[dst - node0], 1);          // LDS atomic
        pairs[p] = (u32)en;                                // bucket-local region
    }
}

// ---------------- gemm1 (r18/r25 verbatim, proven) ----------------
__global__ __launch_bounds__(512) void gemm_kernel(
    const float* xin,
    const float* __restrict__ Wrel, const float* __restrict__ brel,
    const float* __restrict__ Wroot,
    u16* __restrict__ xr, float* io, int Nn)
{
    __shared__ float WrelT[D][D + 1];
    __shared__ float WrootT[D][D + 1];
    __shared__ float bias[D];
    __shared__ float rowX[GW][GR][D];

    int tid = threadIdx.x;
    for (int i = tid; i < D * D; i += 512) {
        int d = i >> 6, k = i & 63;
        WrelT [k][d] = Wrel [i];
        WrootT[k][d] = Wroot[i];
    }
    if (tid < D) bias[tid] = brel[tid];
    __syncthreads();

    int wave = tid >> 6, lane = tid & 63;

    int base = (blockIdx.x * GW + wave) * GR;
    if (base >= Nn) return;             // wave-uniform, after barrier
    int nr = min(GR, Nn - base);

    for (int r = 0; r < nr; ++r)
        rowX[wave][r][lane] = xin[(size_t)(base + r) * D + lane];
    // same-wave LDS write->read (proven)

    float aR[GR] = {0.f, 0.f, 0.f, 0.f};
    float aC[GR] = {0.f, 0.f, 0.f, 0.f};
#pragma unroll
    for (int k4 = 0; k4 < 16; ++k4) {
        float4 xv[GR];
#pragma unroll
        for (int r = 0; r < GR; ++r)
            xv[r] = *reinterpret_cast<const float4*>(&rowX[wave][r][k4 * 4]);
#pragma unroll
        for (int kk = 0; kk < 4; ++kk) {
            float wr = WrelT [k4 * 4 + kk][lane];
            float wc = WrootT[k4 * 4 + kk][lane];
#pragma unroll
            for (int r = 0; r < GR; ++r) {
                float xk = (kk == 0) ? xv[r].x : (kk == 1) ? xv[r].y
                         : (kk == 2) ? xv[r].z : xv[r].w;
                aR[r] = fmaf(xk, wr, aR[r]);
                aC[r] = fmaf(xk, wc, aC[r]);
            }
        }
    }
    for (int r = 0; r < nr; ++r) {
        size_t o = (size_t)(base + r) * D + lane;
        xr[o] = f2bf(aR[r]);
        io[o] = aC[r] + bias[lane];
    }
}

// ---------------- gather1_fused (r25 structure; staging split across halves) ----------------
__global__ __launch_bounds__(512) void gather1_fused(
    const u16* __restrict__ xr1, const u32* __restrict__ pairs,
    const int* __restrict__ rowptr,
    const float* __restrict__ Wrel, const float* __restrict__ brel,
    const float* __restrict__ Wroot,
    u16* __restrict__ xr2, float* __restrict__ io, int Nn)
{
    __shared__ float WrelT[D][D + 1];
    __shared__ float WrootT[D][D + 1];
    __shared__ float bias[D];
    __shared__ float rowH[GW][2][D];

    int tid = threadIdx.x;
    for (int i2 = tid; i2 < D * D; i2 += 512) {
        int d = i2 >> 6, k = i2 & 63;
        WrelT [k][d] = Wrel [i2];
        WrootT[k][d] = Wroot[i2];
    }
    if (tid < D) bias[tid] = brel[tid];
    __syncthreads();

    int wave = tid >> 6, lane = tid & 63;
    int i0 = ((int)blockIdx.x * GW + wave) * 2;
    if (i0 >= Nn) return;                      // wave-uniform, after barrier
    int i1 = i0 + 1;
    bool row1v = (i1 < Nn);
    int i1c = row1v ? i1 : i0;

    int beg0 = __builtin_amdgcn_readfirstlane(rowptr[i0]);
    int end0 = __builtin_amdgcn_readfirstlane(rowptr[i0 + 1]);
    int beg1 = __builtin_amdgcn_readfirstlane(rowptr[i1c]);
    int end1 = __builtin_amdgcn_readfirstlane(rowptr[i1c + 1]);
    int deg0 = end0 - beg0;
    int deg1 = row1v ? (end1 - beg1) : 0;
    int dmax = max(deg0, deg1);

    int half = lane >> 5;                      // 0: edge j, 1: edge j+1
    int c    = lane & 31;                      // feature pair index

    float a00 = 0.f, a01 = 0.f, a10 = 0.f, a11 = 0.f;
    for (int b = 0; b < dmax; b += 16) {       // 16 edge-slots/row/volley
#pragma unroll
        for (int jj = 0; jj < 8; ++jj) {
            int j0 = b + 2 * jj;
            u32 q0 = pairs[beg0 + j0];
            u32 q1 = pairs[beg0 + j0 + 1];
            int   s00 = (j0     < deg0) ? (int)(q0 >> 15) : 0;
            float w00 = (j0     < deg0) ? __uint_as_float((q0 & 0x7FFFu) << 16) : 0.f;
            int   s01 = (j0 + 1 < deg0) ? (int)(q1 >> 15) : 0;
            float w01 = (j0 + 1 < deg0) ? __uint_as_float((q1 & 0x7FFFu) << 16) : 0.f;
            int   sa  = half ? s01 : s00;
            float wa  = half ? w01 : w00;
            u32 va = *reinterpret_cast<const u32*>(xr1 + (size_t)sa * D + c * 2);
            u32 r0 = pairs[beg1 + j0];
            u32 r1 = pairs[beg1 + j0 + 1];
            int   s10 = (j0     < deg1) ? (int)(r0 >> 15) : 0;
            float w10 = (j0     < deg1) ? __uint_as_float((r0 & 0x7FFFu) << 16) : 0.f;
            int   s11 = (j0 + 1 < deg1) ? (int)(r1 >> 15) : 0;
            float w11 = (j0 + 1 < deg1) ? __uint_as_float((r1 & 0x7FFFu) << 16) : 0.f;
            int   sb  = half ? s11 : s10;
            float wb  = half ? w11 : w10;
            u32 vb = *reinterpret_cast<const u32*>(xr1 + (size_t)sb * D + c * 2);

            a00 = fmaf(__uint_as_float(va << 16),          wa, a00);
            a01 = fmaf(__uint_as_float(va & 0xFFFF0000u),  wa, a01);
            a10 = fmaf(__uint_as_float(vb << 16),          wb, a10);
            a11 = fmaf(__uint_as_float(vb & 0xFFFF0000u),  wb, a11);
        }
    }
    a00 += __shfl_xor(a00, 32);                // combine: full sums in BOTH halves
    a01 += __shfl_xor(a01, 32);
    a10 += __shfl_xor(a10, 32);
    a11 += __shfl_xor(a11, 32);

    // staging split across halves: half 0 -> row0, half 1 -> row1 (parallel)
    if (half == 0)
        *reinterpret_cast<float2*>(&rowH[wave][0][c * 2]) = make_float2(a00, a01);
    else
        *reinterpret_cast<float2*>(&rowH[wave][1][c * 2]) = make_float2(a10, a11);
    // same-wave LDS write->read (proven)

    size_t o0 = (size_t)i0 * D + lane;
    float h0 = fmaxf(rowH[wave][0][lane] + io[o0], 0.f);
    rowH[wave][0][lane] = h0;
    size_t o1 = (size_t)i1c * D + lane;
    float h1 = fmaxf(rowH[wave][1][lane] + io[o1], 0.f);
    rowH[wave][1][lane] = h1;

#pragma unroll
    for (int r = 0; r < 2; ++r) {
        if (r == 1 && !row1v) break;
        const float4* rH4 = reinterpret_cast<const float4*>(rowH[wave][r]);
        float aR = 0.f;
        float aC = bias[lane];
#pragma unroll
        for (int k4 = 0; k4 < 16; ++k4) {
            float4 hv = rH4[k4];               // broadcast b128
            int k = k4 * 4;
            aR = fmaf(hv.x, WrelT [k + 0][lane], aR);
            aR = fmaf(hv.y, WrelT [k + 1][lane], aR);
            aR = fmaf(hv.z, WrelT [k + 2][lane], aR);
            aR = fmaf(hv.w, WrelT [k + 3][lane], aR);
            aC = fmaf(hv.x, WrootT[k + 0][lane], aC);
            aC = fmaf(hv.y, WrootT[k + 1][lane], aC);
            aC = fmaf(hv.z, WrootT[k + 2][lane], aC);
            aC = fmaf(hv.w, WrootT[k + 3][lane], aC);
        }
        size_t o = (size_t)(i0 + r) * D + lane;
        xr2[o] = f2bf(aR);
        io[o]  = aC;                           // rows owned by this wave
    }
}

// ---------------- gather2 (r25 structure; RMW split across halves) ----------------
__global__ __launch_bounds__(512) void gather2_kernel(
    const u16* __restrict__ xr, const u32* __restrict__ pairs,
    const int* __restrict__ rowptr, float* __restrict__ io, int Nn)
{
    int tid  = threadIdx.x;
    int wave = tid >> 6, lane = tid & 63;
    int i0 = ((int)blockIdx.x * AW + wave) * 2;
    if (i0 >= Nn) return;                      // wave-uniform
    int i1 = i0 + 1;
    bool row1v = (i1 < Nn);
    int i1c = row1v ? i1 : i0;

    int beg0 = __builtin_amdgcn_readfirstlane(rowptr[i0]);
    int end0 = __builtin_amdgcn_readfirstlane(rowptr[i0 + 1]);
    int beg1 = __builtin_amdgcn_readfirstlane(rowptr[i1c]);
    int end1 = __builtin_amdgcn_readfirstlane(rowptr[i1c + 1]);
    int deg0 = end0 - beg0;
    int deg1 = row1v ? (end1 - beg1) : 0;
    int dmax = max(deg0, deg1);

    int half = lane >> 5;
    int c    = lane & 31;

    float a00 = 0.f, a01 = 0.f, a10 = 0.f, a11 = 0.f;
    for (int b = 0; b < dmax; b += 16) {
#pragma unroll
        for (int jj = 0; jj < 8; ++jj) {
            int j0 = b + 2 * jj;
            u32 q0 = pairs[beg0 + j0];
            u32 q1 = pairs[beg0 + j0 + 1];
            int   s00 = (j0     < deg0) ? (int)(q0 >> 15) : 0;
            float w00 = (j0     < deg0) ? __uint_as_float((q0 & 0x7FFFu) << 16) : 0.f;
            int   s01 = (j0 + 1 < deg0) ? (int)(q1 >> 15) : 0;
            float w01 = (j0 + 1 < deg0) ? __uint_as_float((q1 & 0x7FFFu) << 16) : 0.f;
            int   sa  = half ? s01 : s00;
            float wa  = half ? w01 : w00;
            u32 va = *reinterpret_cast<const u32*>(xr + (size_t)sa * D + c * 2);
            u32 r0 = pairs[beg1 + j0];
            u32 r1 = pairs[beg1 + j0 + 1];
            int   s10 = (j0     < deg1) ? (int)(r0 >> 15) : 0;
            float w10 = (j0     < deg1) ? __uint_as_float((r0 & 0x7FFFu) << 16) : 0.f;
            int   s11 = (j0 + 1 < deg1) ? (int)(r1 >> 15) : 0;
            float w11 = (j0 + 1 < deg1) ? __uint_as_float((r1 & 0x7FFFu) << 16) : 0.f;
            int   sb  = half ? s11 : s10;
            float wb  = half ? w11 : w10;
            u32 vb = *reinterpret_cast<const u32*>(xr + (size_t)sb * D + c * 2);

            a00 = fmaf(__uint_as_float(va << 16),         wa, a00);
            a01 = fmaf(__uint_as_float(va & 0xFFFF0000u), wa, a01);
            a10 = fmaf(__uint_as_float(vb << 16),         wb, a10);
            a11 = fmaf(__uint_as_float(vb & 0xFFFF0000u), wb, a11);
        }
    }
    a00 += __shfl_xor(a00, 32);                // full sums in BOTH halves
    a01 += __shfl_xor(a01, 32);
    a10 += __shfl_xor(a10, 32);
    a11 += __shfl_xor(a11, 32);

    // RMW split across halves: half 0 -> row0, half 1 -> row1 (parallel)
    if (half == 0) {
        float2* p0 = reinterpret_cast<float2*>(&io[(size_t)i0 * D + c * 2]);
        float2 c0 = *p0; c0.x += a00; c0.y += a01; *p0 = c0;
    } else if (row1v) {
        float2* p1 = reinterpret_cast<float2*>(&io[(size_t)i1 * D + c * 2]);
        float2 c1 = *p1; c1.x += a10; c1.y += a11; *p1 = c1;
    }
}

extern "C" void kernel_launch(void* const* d_in, const int* in_sizes, int n_in,
                              void* d_out, int out_size, void* d_ws, size_t ws_size,
                              hipStream_t stream)
{
    const float* x      = (const float*)d_in[0];
    const int*   ei     = (const int*)  d_in[1];
    const float* ew     = (const float*)d_in[2];
    const float* Wrel1  = (const float*)d_in[3];
    const float* brel1  = (const float*)d_in[4];
    const float* Wroot1 = (const float*)d_in[5];
    const float* Wrel2  = (const float*)d_in[6];
    const float* brel2  = (const float*)d_in[7];
    const float* Wroot2 = (const float*)d_in[8];
    float* out = (float*)d_out;

    const int E_ = in_sizes[2];          // 1600000
    const int Nn = in_sizes[0] / D;      // 100000
    const int nb = (Nn + 511) >> 9;      // 196 buckets

    // workspace layout (~33 MB; bucketBuf 16.1MB ALIASES xr1/xr2 — dead until gemm1)
    char* w = (char*)d_ws;
    size_t off = 0;
    u16*  xr1    = (u16*)(w + off); off += (size_t)Nn * D * sizeof(u16);   // 12.8 MB
    u16*  xr2    = (u16*)(w + off); off += (size_t)Nn * D * sizeof(u16);   // 12.8 MB
    uint64_t* bucketBuf = (uint64_t*)d_ws;                                 // alias, 16.1 MB
    int*  rowptr = (int*)(w + off); off += (size_t)(Nn + 1) * sizeof(int);
    int*  loc    = (int*)(w + off); off += (size_t)Nn * sizeof(int);
    int*  bucketCnt = (int*)(w + off); off += NBMAX * sizeof(int);
    int*  partial= (int*)(w + off); off += 1024 * sizeof(int);
    off = (off + 15) & ~(size_t)15;
    u32* pairs = (u32*)(w + off);                                          // 6.4 MB + 256B pad

    const int aBlocks = (E_ + EPB - 1) / EPB;            // 782
    const int gemmBlocks = (Nn + GW * GR - 1) / (GW * GR);
    const int g1Blocks   = (Nn + GW * 2 - 1) / (GW * 2); // 2 rows/wave
    const int g2Blocks   = (Nn + AW * 2 - 1) / (AW * 2);

    // ---- binned CSR build (5 dispatches) ----
    (void)hipMemsetAsync(bucketCnt, 0, NBMAX * sizeof(int), stream);
    binA_kernel<<<aBlocks, 512, 0, stream>>>(ei, ew, bucketCnt, bucketBuf, E_, nb);
    degscan_kernel<<<nb, 256, 0, stream>>>(bucketBuf, bucketCnt, loc, partial, nb, Nn);
    scan2_kernel<<<1, 1024, 0, stream>>>(partial, nb);
    binB2_kernel<<<nb, 256, 0, stream>>>(bucketBuf, bucketCnt, loc, partial,
                                         rowptr, pairs, nb, Nn, E_);

    // ---- layer 1 pre-transform ----
    gemm_kernel<<<gemmBlocks, 512, 0, stream>>>(x, Wrel1, brel1, Wroot1, xr1, out, Nn);
    // ---- gather1 + relu + layer-2 pre-transform (fused epilogue) ----
    gather1_fused<<<g1Blocks, 512, 0, stream>>>(xr1, pairs, rowptr,
                                                Wrel2, brel2, Wroot2, xr2, out, Nn);
    // ---- gather2 (final) ----
    gather2_kernel<<<g2Blocks, 512, 0, stream>>>(xr2, pairs, rowptr, out, Nn);
}

// Round 28
// 235.394 us; speedup vs baseline: 1.2030x; 1.0014x over previous
//
#include <hip/hip_runtime.h>
#include <hip/hip_bf16.h>
#include <stdint.h>

// GraphConv x2 — round 28: r27 base (235.7us best) + front-end merge:
//   binB3 = degscan + scan2 + binB2 in ONE kernel (bucket base = prefix sum of
//   bucketCnt, computed per-block via LDS atomics — bucketTot==bucketCnt).
//   Front end: memset, binA, binB3 (was 5 dispatches -> 3); `loc` eliminated.
//   Heavy kernels r27-verbatim (gather VGPR 32 / occ 69% preserved).
// N=100000, E=1600000, D=64

#define D 64
#define EPB   2048     // edges per binA tile (16KB LDS)
#define EPT   4        // edges per thread in binA
#define NBMAX 256
#define CAPB  10240
#define GW 8
#define GR 4
#define AW 8

typedef unsigned int   u32;
typedef unsigned short u16;

__device__ __forceinline__ float bf2f(u16 v) {
    return __uint_as_float(((u32)v) << 16);
}
__device__ __forceinline__ u16 f2bf(float f) {
    u32 u = __float_as_uint(f);
    u32 r = (u + 0x7fffu + ((u >> 16) & 1u)) >> 16;   // round-to-nearest-even
    return (u16)r;
}

// ---------------- binA: LDS-binned edge scatter (r24/r27 verbatim) ----------------
__global__ __launch_bounds__(512) void binA_kernel(
    const int* __restrict__ ei, const float* __restrict__ ew,
    int* __restrict__ bucketCnt, uint64_t* __restrict__ bucketBuf, int E_, int nb)
{
    __shared__ uint64_t lds_e[EPB];      // 16 KB
    __shared__ int lcnt[NBMAX];
    __shared__ int loff[NBMAX];
    __shared__ int gbase[NBMAX];

    int tid  = threadIdx.x;
    int tile = blockIdx.x * EPB;
    int cnt  = min(EPB, E_ - tile);
    if (cnt <= 0) return;

    for (int k = tid; k < nb; k += 512) lcnt[k] = 0;
    __syncthreads();

    bool     val[EPT];
    int      lp[EPT], bk[EPT];
    uint64_t ent[EPT];
#pragma unroll
    for (int j = 0; j < EPT; ++j) {
        int l = j * 512 + tid;
        val[j] = (l < cnt);
        if (val[j]) {
            int e   = tile + l;
            int src = ei[e];
            int dst = ei[E_ + e];
            u32 wb  = (u32)f2bf(ew[e]) & 0x7FFFu;
            u32 p32 = ((u32)src << 15) | wb;               // r17 pack
            int b   = dst >> 9;
            ent[j] = ((uint64_t)(u32)dst << 32) | p32;
            bk[j]  = b;
            lp[j]  = atomicAdd(&lcnt[b], 1);               // LDS atomic
        }
    }
    __syncthreads();

    if (tid == 0) {                                        // exclusive scan
        int run = 0;
        for (int b = 0; b < nb; ++b) { int c = lcnt[b]; loff[b] = run; run += c; }
    }
    __syncthreads();
    if (tid < nb) gbase[tid] = atomicAdd(&bucketCnt[tid], lcnt[tid]);
    __syncthreads();

#pragma unroll
    for (int j = 0; j < EPT; ++j)
        if (val[j]) lds_e[loff[bk[j]] + lp[j]] = ent[j];   // group by bucket in LDS
    __syncthreads();

    for (int k = tid; k < cnt; k += 512) {
        uint64_t en = lds_e[k];
        int b   = (int)(en >> 41);                         // dst>>9
        int gp  = gbase[b] + (k - loff[b]);
        if (gp < CAPB)
            bucketBuf[(size_t)b * CAPB + gp] = en;
    }
}

// ---------------- binB3: histogram + scan + rowptr + drain, one kernel ----------------
__global__ __launch_bounds__(256) void binB3_kernel(
    const uint64_t* __restrict__ bucketBuf, const int* __restrict__ bucketCnt,
    int* __restrict__ rowptr, u32* __restrict__ pairs, int nb, int Nn, int E_)
{
    __shared__ int ldeg[512];
    __shared__ int lcur[512];
    __shared__ int wsum[4];
    __shared__ int sbase;
    int b = blockIdx.x;
    if (b >= nb) return;
    int node0 = b << 9;
    int tid = threadIdx.x;

    // bucket base = sum of clamped counts of preceding buckets (bucketTot==bucketCnt)
    if (tid == 0) sbase = 0;
    for (int k = tid; k < 512; k += 256) ldeg[k] = 0;
    __syncthreads();
    if (tid < b) atomicAdd(&sbase, min(bucketCnt[tid], CAPB));   // <=195 LDS atomics
    // histogram of this bucket
    int cnt = min(bucketCnt[b], CAPB);
    for (int k = tid; k < cnt; k += 256)
        atomicAdd(&ldeg[((int)(bucketBuf[(size_t)b * CAPB + k] >> 32)) - node0], 1);
    __syncthreads();
    int base = sbase;

    // exclusive scan of 512 entries (2/thread, proven wave-scan pattern)
    int v0 = ldeg[2 * tid], v1 = ldeg[2 * tid + 1];
    int s = v0 + v1;
    int lane = tid & 63, wave = tid >> 6;
    int inc = s;
    for (int off = 1; off < 64; off <<= 1) {
        int u = __shfl_up(inc, off);
        if (lane >= off) inc += u;
    }
    if (lane == 63) wsum[wave] = inc;
    __syncthreads();
    int woff = 0;
    for (int w2 = 0; w2 < wave; ++w2) woff += wsum[w2];
    int ex = woff + inc - s;
    int n0 = node0 + 2 * tid;
    if (n0 < Nn)     { int v = base + ex;      lcur[2 * tid]     = v; rowptr[n0]     = v; }
    if (n0 + 1 < Nn) { int v = base + ex + v0; lcur[2 * tid + 1] = v; rowptr[n0 + 1] = v; }
    if (b == nb - 1 && tid == 0) rowptr[Nn] = E_;
    __syncthreads();

    // drain into pairs (LDS cursor; bucket-local L2 region)
    for (int k = tid; k < cnt; k += 256) {
        uint64_t en = bucketBuf[(size_t)b * CAPB + k];
        int dst = (int)(en >> 32);
        int p = atomicAdd(&lcur[dst - node0], 1);          // LDS atomic
        pairs[p] = (u32)en;
    }
}

// ---------------- gemm1 (r18/r27 verbatim, proven) ----------------
__global__ __launch_bounds__(512) void gemm_kernel(
    const float* xin,
    const float* __restrict__ Wrel, const float* __restrict__ brel,
    const float* __restrict__ Wroot,
    u16* __restrict__ xr, float* io, int Nn)
{
    __shared__ float WrelT[D][D + 1];
    __shared__ float WrootT[D][D + 1];
    __shared__ float bias[D];
    __shared__ float rowX[GW][GR][D];

    int tid = threadIdx.x;
    for (int i = tid; i < D * D; i += 512) {
        int d = i >> 6, k = i & 63;
        WrelT [k][d] = Wrel [i];
        WrootT[k][d] = Wroot[i];
    }
    if (tid < D) bias[tid] = brel[tid];
    __syncthreads();

    int wave = tid >> 6, lane = tid & 63;

    int base = (blockIdx.x * GW + wave) * GR;
    if (base >= Nn) return;             // wave-uniform, after barrier
    int nr = min(GR, Nn - base);

    for (int r = 0; r < nr; ++r)
        rowX[wave][r][lane] = xin[(size_t)(base + r) * D + lane];
    // same-wave LDS write->read (proven)

    float aR[GR] = {0.f, 0.f, 0.f, 0.f};
    float aC[GR] = {0.f, 0.f, 0.f, 0.f};
#pragma unroll
    for (int k4 = 0; k4 < 16; ++k4) {
        float4 xv[GR];
#pragma unroll
        for (int r = 0; r < GR; ++r)
            xv[r] = *reinterpret_cast<const float4*>(&rowX[wave][r][k4 * 4]);
#pragma unroll
        for (int kk = 0; kk < 4; ++kk) {
            float wr = WrelT [k4 * 4 + kk][lane];
            float wc = WrootT[k4 * 4 + kk][lane];
#pragma unroll
            for (int r = 0; r < GR; ++r) {
                float xk = (kk == 0) ? xv[r].x : (kk == 1) ? xv[r].y
                         : (kk == 2) ? xv[r].z : xv[r].w;
                aR[r] = fmaf(xk, wr, aR[r]);
                aC[r] = fmaf(xk, wc, aC[r]);
            }
        }
    }
    for (int r = 0; r < nr; ++r) {
        size_t o = (size_t)(base + r) * D + lane;
        xr[o] = f2bf(aR[r]);
        io[o] = aC[r] + bias[lane];
    }
}

// ---------------- gather1_fused (r27 verbatim: half-split staging, VGPR 32) ----------------
__global__ __launch_bounds__(512) void gather1_fused(
    const u16* __restrict__ xr1, const u32* __restrict__ pairs,
    const int* __restrict__ rowptr,
    const float* __restrict__ Wrel, const float* __restrict__ brel,
    const float* __restrict__ Wroot,
    u16* __restrict__ xr2, float* __restrict__ io, int Nn)
{
    __shared__ float WrelT[D][D + 1];
    __shared__ float WrootT[D][D + 1];
    __shared__ float bias[D];
    __shared__ float rowH[GW][2][D];

    int tid = threadIdx.x;
    for (int i2 = tid; i2 < D * D; i2 += 512) {
        int d = i2 >> 6, k = i2 & 63;
        WrelT [k][d] = Wrel [i2];
        WrootT[k][d] = Wroot[i2];
    }
    if (tid < D) bias[tid] = brel[tid];
    __syncthreads();

    int wave = tid >> 6, lane = tid & 63;
    int i0 = ((int)blockIdx.x * GW + wave) * 2;
    if (i0 >= Nn) return;                      // wave-uniform, after barrier
    int i1 = i0 + 1;
    bool row1v = (i1 < Nn);
    int i1c = row1v ? i1 : i0;

    int beg0 = __builtin_amdgcn_readfirstlane(rowptr[i0]);
    int end0 = __builtin_amdgcn_readfirstlane(rowptr[i0 + 1]);
    int beg1 = __builtin_amdgcn_readfirstlane(rowptr[i1c]);
    int end1 = __builtin_amdgcn_readfirstlane(rowptr[i1c + 1]);
    int deg0 = end0 - beg0;
    int deg1 = row1v ? (end1 - beg1) : 0;
    int dmax = max(deg0, deg1);

    int half = lane >> 5;                      // 0: edge j, 1: edge j+1
    int c    = lane & 31;                      // feature pair index

    float a00 = 0.f, a01 = 0.f, a10 = 0.f, a11 = 0.f;
    for (int b = 0; b < dmax; b += 16) {       // 16 edge-slots/row/volley
#pragma unroll
        for (int jj = 0; jj < 8; ++jj) {
            int j0 = b + 2 * jj;
            u32 q0 = pairs[beg0 + j0];
            u32 q1 = pairs[beg0 + j0 + 1];
            int   s00 = (j0     < deg0) ? (int)(q0 >> 15) : 0;
            float w00 = (j0     < deg0) ? __uint_as_float((q0 & 0x7FFFu) << 16) : 0.f;
            int   s01 = (j0 + 1 < deg0) ? (int)(q1 >> 15) : 0;
            float w01 = (j0 + 1 < deg0) ? __uint_as_float((q1 & 0x7FFFu) << 16) : 0.f;
            int   sa  = half ? s01 : s00;
            float wa  = half ? w01 : w00;
            u32 va = *reinterpret_cast<const u32*>(xr1 + (size_t)sa * D + c * 2);
            u32 r0 = pairs[beg1 + j0];
            u32 r1 = pairs[beg1 + j0 + 1];
            int   s10 = (j0     < deg1) ? (int)(r0 >> 15) : 0;
            float w10 = (j0     < deg1) ? __uint_as_float((r0 & 0x7FFFu) << 16) : 0.f;
            int   s11 = (j0 + 1 < deg1) ? (int)(r1 >> 15) : 0;
            float w11 = (j0 + 1 < deg1) ? __uint_as_float((r1 & 0x7FFFu) << 16) : 0.f;
            int   sb  = half ? s11 : s10;
            float wb  = half ? w11 : w10;
            u32 vb = *reinterpret_cast<const u32*>(xr1 + (size_t)sb * D + c * 2);

            a00 = fmaf(__uint_as_float(va << 16),          wa, a00);
            a01 = fmaf(__uint_as_float(va & 0xFFFF0000u),  wa, a01);
            a10 = fmaf(__uint_as_float(vb << 16),          wb, a10);
            a11 = fmaf(__uint_as_float(vb & 0xFFFF0000u),  wb, a11);
        }
    }
    a00 += __shfl_xor(a00, 32);                // combine: full sums in BOTH halves
    a01 += __shfl_xor(a01, 32);
    a10 += __shfl_xor(a10, 32);
    a11 += __shfl_xor(a11, 32);

    // staging split across halves: half 0 -> row0, half 1 -> row1 (parallel)
    if (half == 0)
        *reinterpret_cast<float2*>(&rowH[wave][0][c * 2]) = make_float2(a00, a01);
    else
        *reinterpret_cast<float2*>(&rowH[wave][1][c * 2]) = make_float2(a10, a11);
    // same-wave LDS write->read (proven)

    size_t o0 = (size_t)i0 * D + lane;
    float h0 = fmaxf(rowH[wave][0][lane] + io[o0], 0.f);
    rowH[wave][0][lane] = h0;
    size_t o1 = (size_t)i1c * D + lane;
    float h1 = fmaxf(rowH[wave][1][lane] + io[o1], 0.f);
    rowH[wave][1][lane] = h1;

#pragma unroll
    for (int r = 0; r < 2; ++r) {
        if (r == 1 && !row1v) break;
        const float4* rH4 = reinterpret_cast<const float4*>(rowH[wave][r]);
        float aR = 0.f;
        float aC = bias[lane];
#pragma unroll
        for (int k4 = 0; k4 < 16; ++k4) {
            float4 hv = rH4[k4];               // broadcast b128
            int k = k4 * 4;
            aR = fmaf(hv.x, WrelT [k + 0][lane], aR);
            aR = fmaf(hv.y, WrelT [k + 1][lane], aR);
            aR = fmaf(hv.z, WrelT [k + 2][lane], aR);
            aR = fmaf(hv.w, WrelT [k + 3][lane], aR);
            aC = fmaf(hv.x, WrootT[k + 0][lane], aC);
            aC = fmaf(hv.y, WrootT[k + 1][lane], aC);
            aC = fmaf(hv.z, WrootT[k + 2][lane], aC);
            aC = fmaf(hv.w, WrootT[k + 3][lane], aC);
        }
        size_t o = (size_t)(i0 + r) * D + lane;
        xr2[o] = f2bf(aR);
        io[o]  = aC;                           // rows owned by this wave
    }
}

// ---------------- gather2 (r27 verbatim: half-split RMW) ----------------
__global__ __launch_bounds__(512) void gather2_kernel(
    const u16* __restrict__ xr, const u32* __restrict__ pairs,
    const int* __restrict__ rowptr, float* __restrict__ io, int Nn)
{
    int tid  = threadIdx.x;
    int wave = tid >> 6, lane = tid & 63;
    int i0 = ((int)blockIdx.x * AW + wave) * 2;
    if (i0 >= Nn) return;                      // wave-uniform
    int i1 = i0 + 1;
    bool row1v = (i1 < Nn);
    int i1c = row1v ? i1 : i0;

    int beg0 = __builtin_amdgcn_readfirstlane(rowptr[i0]);
    int end0 = __builtin_amdgcn_readfirstlane(rowptr[i0 + 1]);
    int beg1 = __builtin_amdgcn_readfirstlane(rowptr[i1c]);
    int end1 = __builtin_amdgcn_readfirstlane(rowptr[i1c + 1]);
    int deg0 = end0 - beg0;
    int deg1 = row1v ? (end1 - beg1) : 0;
    int dmax = max(deg0, deg1);

    int half = lane >> 5;
    int c    = lane & 31;

    float a00 = 0.f, a01 = 0.f, a10 = 0.f, a11 = 0.f;
    for (int b = 0; b < dmax; b += 16) {
#pragma unroll
        for (int jj = 0; jj < 8; ++jj) {
            int j0 = b + 2 * jj;
            u32 q0 = pairs[beg0 + j0];
            u32 q1 = pairs[beg0 + j0 + 1];
            int   s00 = (j0     < deg0) ? (int)(q0 >> 15) : 0;
            float w00 = (j0     < deg0) ? __uint_as_float((q0 & 0x7FFFu) << 16) : 0.f;
            int   s01 = (j0 + 1 < deg0) ? (int)(q1 >> 15) : 0;
            float w01 = (j0 + 1 < deg0) ? __uint_as_float((q1 & 0x7FFFu) << 16) : 0.f;
            int   sa  = half ? s01 : s00;
            float wa  = half ? w01 : w00;
            u32 va = *reinterpret_cast<const u32*>(xr + (size_t)sa * D + c * 2);
            u32 r0 = pairs[beg1 + j0];
            u32 r1 = pairs[beg1 + j0 + 1];
            int   s10 = (j0     < deg1) ? (int)(r0 >> 15) : 0;
            float w10 = (j0     < deg1) ? __uint_as_float((r0 & 0x7FFFu) << 16) : 0.f;
            int   s11 = (j0 + 1 < deg1) ? (int)(r1 >> 15) : 0;
            float w11 = (j0 + 1 < deg1) ? __uint_as_float((r1 & 0x7FFFu) << 16) : 0.f;
            int   sb  = half ? s11 : s10;
            float wb  = half ? w11 : w10;
            u32 vb = *reinterpret_cast<const u32*>(xr + (size_t)sb * D + c * 2);

            a00 = fmaf(__uint_as_float(va << 16),         wa, a00);
            a01 = fmaf(__uint_as_float(va & 0xFFFF0000u), wa, a01);
            a10 = fmaf(__uint_as_float(vb << 16),         wb, a10);
            a11 = fmaf(__uint_as_float(vb & 0xFFFF0000u), wb, a11);
        }
    }
    a00 += __shfl_xor(a00, 32);                // full sums in BOTH halves
    a01 += __shfl_xor(a01, 32);
    a10 += __shfl_xor(a10, 32);
    a11 += __shfl_xor(a11, 32);

    // RMW split across halves: half 0 -> row0, half 1 -> row1 (parallel)
    if (half == 0) {
        float2* p0 = reinterpret_cast<float2*>(&io[(size_t)i0 * D + c * 2]);
        float2 c0 = *p0; c0.x += a00; c0.y += a01; *p0 = c0;
    } else if (row1v) {
        float2* p1 = reinterpret_cast<float2*>(&io[(size_t)i1 * D + c * 2]);
        float2 c1 = *p1; c1.x += a10; c1.y += a11; *p1 = c1;
    }
}

extern "C" void kernel_launch(void* const* d_in, const int* in_sizes, int n_in,
                              void* d_out, int out_size, void* d_ws, size_t ws_size,
                              hipStream_t stream)
{
    const float* x      = (const float*)d_in[0];
    const int*   ei     = (const int*)  d_in[1];
    const float* ew     = (const float*)d_in[2];
    const float* Wrel1  = (const float*)d_in[3];
    const float* brel1  = (const float*)d_in[4];
    const float* Wroot1 = (const float*)d_in[5];
    const float* Wrel2  = (const float*)d_in[6];
    const float* brel2  = (const float*)d_in[7];
    const float* Wroot2 = (const float*)d_in[8];
    float* out = (float*)d_out;

    const int E_ = in_sizes[2];          // 1600000
    const int Nn = in_sizes[0] / D;      // 100000
    const int nb = (Nn + 511) >> 9;      // 196 buckets

    // workspace layout (~33 MB; bucketBuf 16.1MB ALIASES xr1/xr2 — dead until gemm1)
    char* w = (char*)d_ws;
    size_t off = 0;
    u16*  xr1    = (u16*)(w + off); off += (size_t)Nn * D * sizeof(u16);   // 12.8 MB
    u16*  xr2    = (u16*)(w + off); off += (size_t)Nn * D * sizeof(u16);   // 12.8 MB
    uint64_t* bucketBuf = (uint64_t*)d_ws;                                 // alias, 16.1 MB
    int*  rowptr = (int*)(w + off); off += (size_t)(Nn + 1) * sizeof(int);
    int*  bucketCnt = (int*)(w + off); off += NBMAX * sizeof(int);
    off = (off + 15) & ~(size_t)15;
    u32* pairs = (u32*)(w + off);                                          // 6.4 MB + 256B pad

    const int aBlocks = (E_ + EPB - 1) / EPB;            // 782
    const int gemmBlocks = (Nn + GW * GR - 1) / (GW * GR);
    const int g1Blocks   = (Nn + GW * 2 - 1) / (GW * 2); // 2 rows/wave
    const int g2Blocks   = (Nn + AW * 2 - 1) / (AW * 2);

    // ---- binned CSR build (3 dispatches) ----
    (void)hipMemsetAsync(bucketCnt, 0, NBMAX * sizeof(int), stream);
    binA_kernel<<<aBlocks, 512, 0, stream>>>(ei, ew, bucketCnt, bucketBuf, E_, nb);
    binB3_kernel<<<nb, 256, 0, stream>>>(bucketBuf, bucketCnt, rowptr, pairs, nb, Nn, E_);

    // ---- layer 1 pre-transform ----
    gemm_kernel<<<gemmBlocks, 512, 0, stream>>>(x, Wrel1, brel1, Wroot1, xr1, out, Nn);
    // ---- gather1 + relu + layer-2 pre-transform (fused epilogue) ----
    gather1_fused<<<g1Blocks, 512, 0, stream>>>(xr1, pairs, rowptr,
                                                Wrel2, brel2, Wroot2, xr2, out, Nn);
    // ---- gather2 (final) ----
    gather2_kernel<<<g2Blocks, 512, 0, stream>>>(xr2, pairs, rowptr, out, Nn);
}